// Round 4
// baseline (794.462 us; speedup 1.0000x reference)
//
#include <hip/hip_runtime.h>
#include <hip/hip_fp16.h>

#define BB 32
#define HH 512
#define WW 512
#define NQROW (WW / 4)            // 128 float4 per row
#define NPIX_F 8388608.0f         // 32*512*512
#define QPAD 4
#define NQP (NQROW + 2 * QPAD)    // 136
#define R1 16
#define NSTR1 (HH / R1)           // 32
#define NB1 (BB * NSTR1 * 2)      // 2048 pass-1 blocks
#define ROWS2 2
#define NB2 (BB * HH / ROWS2)     // 8192 pass-2 blocks (2 waves each)
#define NWAVE2 (BB * HH)          // 16384 row-waves
#define V_OFF_BYTES 1024
#define WS_NEED (V_OFF_BYTES + (size_t)BB * HH * WW * 2)

// two-pass ws layout (floats):
//   [0..31]   bce partials (per image)
//   [32..63]  w_sum
//   [64..95]  intersection
//   [96..127] union
//   [128]     completion counter (int) — zeroed by hipMemsetAsync each launch
// V (fp16, [B][H][W]) at byte offset 1024.

__device__ __forceinline__ void elemwise4(const float h0, const float h1,
                                          const float h2, const float h3,
                                          const float4 t, const float4 p,
                                          float& a_bce, float& a_w,
                                          float& a_i, float& a_u)
{
    const float hv[4] = {h0, h1, h2, h3};
    const float tv[4] = {t.x, t.y, t.z, t.w};
    const float pv[4] = {p.x, p.y, p.z, p.w};
    const float inv961 = (1.0f / 961.0f);
    #pragma unroll
    for (int j = 0; j < 4; ++j) {
        const float ap = hv[j] * inv961;
        const float w  = fmaf(5.0f, fabsf(ap - tv[j]), 1.0f);
        const float pr = pv[j];
        const float ea = __expf(-fabsf(pr));                  // exp(-|pr|)
        const float iv = __builtin_amdgcn_rcpf(1.0f + ea);
        const float pp = (pr >= 0.0f) ? iv : (1.0f - iv);     // sigmoid
        const float sp = fmaxf(pr, 0.0f) + __logf(1.0f + ea); // softplus
        a_bce += sp - pr * tv[j];
        a_w   += w;
        a_i   += pp * tv[j] * w;
        a_u   += (pp + tv[j]) * w;
    }
}

// ---------------- Pass 1: vertical 31-row running sums -> V (fp16) -------
__global__ __launch_bounds__(64)
void vpass_kernel(const float* __restrict__ targ, __half* __restrict__ V)
{
    const int lane = threadIdx.x;
    const int bi = blockIdx.x;
    const int halfc  = bi & 1;
    const int stripe = (bi >> 1) & (NSTR1 - 1);
    const int b      = bi >> 6;
    const int r0 = stripe * R1;
    const int cq = halfc * 64 + lane;       // quad index 0..127

    const float4* t4 = (const float4*)(targ + (size_t)b * (HH * WW));
    const float4 Z4 = make_float4(0.f, 0.f, 0.f, 0.f);
    auto ld = [&](int yy) -> float4 {
        return (yy >= 0 && yy < HH) ? t4[(size_t)yy * NQROW + cq] : Z4;
    };

    float a0 = 0.f, a1 = 0.f, a2 = 0.f, a3 = 0.f;
    float4 nb[4], sb[2];
    nb[0] = ld(r0 - 15); nb[1] = ld(r0 - 14);
    nb[2] = ld(r0 - 13); nb[3] = ld(r0 - 12);
    sb[0] = ld(r0 - 15); sb[1] = ld(r0 - 14);

    __half* Vb = V + (size_t)b * (HH * WW) + cq * 4;

    #pragma unroll
    for (int k = 0; k < 46; ++k) {          // row r0-15+k enters the window
        const float4 a = nb[k & 3];
        if (k + 4 < 46) nb[k & 3] = ld(r0 - 15 + k + 4);
        a0 += a.x; a1 += a.y; a2 += a.z; a3 += a.w;
        if (k >= 30) {
            const int y = r0 + k - 30;      // window = rows y-15..y+15
            const __half2 h01 = __floats2half2_rn(a0, a1);
            const __half2 h23 = __floats2half2_rn(a2, a3);
            uint2 pk;
            pk.x = __builtin_bit_cast(unsigned int, h01);
            pk.y = __builtin_bit_cast(unsigned int, h23);
            *(uint2*)(Vb + (size_t)y * WW) = pk;
            const float4 s = sb[k & 1];
            if (k + 2 < 46) sb[k & 1] = ld(r0 + k - 43);
            a0 -= s.x; a1 -= s.y; a2 -= s.z; a3 -= s.w;
        }
    }
}

// -------- Pass 2: horizontal 31-sum + elementwise + reduce + finalize ----
__global__ __launch_bounds__(128)
void hpass_kernel(const float* __restrict__ pred, const float* __restrict__ targ,
                  const __half* __restrict__ V, float* __restrict__ ws,
                  float* __restrict__ out)
{
    const int lane = threadIdx.x & 63;
    const int wv   = threadIdx.x >> 6;              // 0..1, independent waves
    const int gr   = blockIdx.x * ROWS2 + wv;       // global row id
    const int b = gr >> 9;

    __shared__ float4 ebuf[ROWS2][NQP];
    __shared__ float  locq[ROWS2][NQP];

    const float4 Z4 = make_float4(0.f, 0.f, 0.f, 0.f);
    if (lane < 2 * QPAD) {                          // zero x-halo pads
        const int idx = (lane < QPAD) ? lane : (NQROW + lane);
        ebuf[wv][idx] = Z4;
        locq[wv][idx] = 0.f;
    }

    // issue ALL global loads up front (one latency exposure per wave)
    const size_t rowoff = (size_t)gr * WW;
    const uint4 vv = ((const uint4*)(V + rowoff))[lane];   // 8 fp16
    const float4* t4 = (const float4*)(targ + rowoff);
    const float4* p4 = (const float4*)(pred + rowoff);
    const float4 tA = t4[lane], tB = t4[64 + lane];
    const float4 pA = p4[lane], pB = p4[64 + lane];

    // unpack V -> cols 8*lane .. 8*lane+7 = quads 2*lane, 2*lane+1
    const __half2 v01 = __builtin_bit_cast(__half2, vv.x);
    const __half2 v23 = __builtin_bit_cast(__half2, vv.y);
    const __half2 v45 = __builtin_bit_cast(__half2, vv.z);
    const __half2 v67 = __builtin_bit_cast(__half2, vv.w);
    const float2 f01 = __half22float2(v01), f23 = __half22float2(v23);
    const float2 f45 = __half22float2(v45), f67 = __half22float2(v67);
    const float4 lo = make_float4(f01.x, f01.y, f23.x, f23.y);
    const float4 hi = make_float4(f45.x, f45.y, f67.x, f67.y);
    ebuf[wv][QPAD + 2 * lane]     = lo;
    locq[wv][QPAD + 2 * lane]     = lo.x + lo.y + lo.z + lo.w;
    ebuf[wv][QPAD + 2 * lane + 1] = hi;
    locq[wv][QPAD + 2 * lane + 1] = hi.x + hi.y + hi.z + hi.w;
    __builtin_amdgcn_wave_barrier();   // single-wave LDS exchange; lgkmcnt
                                       // ordering inserted by the compiler

    float a_bce = 0.f, a_w = 0.f, a_i = 0.f, a_u = 0.f;
    #pragma unroll
    for (int half2_ = 0; half2_ < 2; ++half2_) {
        const int q = half2_ * 64 + lane;           // owned quad
        float F = 0.f;
        #pragma unroll
        for (int k = -3; k <= 3; ++k) F += locq[wv][QPAD + q + k];
        const float4 L = ebuf[wv][QPAD + q - 4];
        const float4 U = ebuf[wv][QPAD + q + 4];
        const float h0 = F + L.y + L.z + L.w;       // col 4q: [4q-15..4q+15]
        const float h1 = F + L.z + L.w + U.x;
        const float h2 = F + L.w + U.x + U.y;
        const float h3 = F + U.x + U.y + U.z;
        elemwise4(h0, h1, h2, h3,
                  half2_ ? tB : tA, half2_ ? pB : pA,
                  a_bce, a_w, a_i, a_u);
    }

    #pragma unroll
    for (int off = 32; off > 0; off >>= 1) {
        a_bce += __shfl_down(a_bce, off, 64);
        a_w   += __shfl_down(a_w,   off, 64);
        a_i   += __shfl_down(a_i,   off, 64);
        a_u   += __shfl_down(a_u,   off, 64);
    }
    if (lane == 0) {
        atomicAdd(&ws[b],      a_bce);
        atomicAdd(&ws[32 + b], a_w);
        atomicAdd(&ws[64 + b], a_i);
        atomicAdd(&ws[96 + b], a_u);
    }
    __threadfence();

    int last = 0;
    if (lane == 0) {
        const int old = atomicAdd((int*)(ws + 128), 1);
        last = (old == NWAVE2 - 1);
    }
    last = __shfl(last, 0, 64);
    if (last) {
        __threadfence();
        // read partials at the coherent point (same scope as the writes)
        float bsum = 0.f;
        if (lane < 32) bsum = atomicAdd(&ws[lane], 0.0f);
        #pragma unroll
        for (int off = 16; off > 0; off >>= 1) bsum += __shfl_down(bsum, off, 64);
        const float bce = __shfl(bsum, 0, 64) * (1.0f / NPIX_F);

        float val = 0.f;
        if (lane < 32) {
            const float wsum  = atomicAdd(&ws[32 + lane], 0.0f);
            const float inter = atomicAdd(&ws[64 + lane], 0.0f);
            const float uni   = atomicAdd(&ws[96 + lane], 0.0f);
            const float w_bce = (wsum * bce + 1e-8f) / (wsum + 1e-8f);
            const float w_iou = 1.0f - (inter + 1.0f + 1e-8f) / (uni - inter + 1.0f + 1e-8f);
            val = w_bce + w_iou;
        }
        #pragma unroll
        for (int off = 16; off > 0; off >>= 1) val += __shfl_down(val, off, 64);
        if (lane == 0) out[0] = val * (1.0f / BB);
    }
}

// ================= fallback (validated round-2 fused path) ===============
#define PADK 15
#define RROWS 32
#define NSTRIPES (HH / RROWS)
#define NCH 2
#define COLS (WW / NCH)
#define CQ (COLS / 4)
#define FNQP (CQ + 2 * QPAD)
#define NSTEPS (RROWS + 2 * PADK)

__global__ __launch_bounds__(64)
void fused_pool_loss_kernel(const float* __restrict__ pred,
                            const float* __restrict__ targ,
                            float* __restrict__ ws)
{
    const int lane = threadIdx.x;
    const int bi   = blockIdx.x;
    const int half   = bi & 1;
    const int stripe = (bi >> 1) & (NSTRIPES - 1);
    const int b      = bi >> 5;
    const int r0  = stripe * RROWS;
    const int cq0 = half * CQ;

    __shared__ __half2 ring[31][2][64];
    __shared__ float4  ebuf[2][FNQP];
    __shared__ float   locq[2][FNQP];

    {
        const __half2 z2 = __floats2half2_rn(0.f, 0.f);
        __half2* rp = &ring[0][0][0];
        for (int i = lane; i < 31 * 2 * 64; i += 64) rp[i] = z2;
    }
    __builtin_amdgcn_wave_barrier();

    const float4* targ4 = (const float4*)(targ + (size_t)b * HH * WW);
    const float4* pred4 = (const float4*)(pred + (size_t)b * HH * WW);
    const float4 Z4 = make_float4(0.f, 0.f, 0.f, 0.f);

    const int hq = (lane < 4) ? (cq0 - QPAD + lane) : (cq0 + CQ + (lane - 4));
    const bool hq_ok = (lane < 8) && (hq >= 0) && (hq < NQROW);
    const int hslot = (lane < 4) ? lane : (CQ + QPAD + (lane - 4));

    auto ld_row = [&](int step, float4& m, float4& h) {
        m = Z4; h = Z4;
        const int yy = r0 - PADK + step;
        if (step < NSTEPS && yy >= 0 && yy < HH) {
            const float4* rp = targ4 + (size_t)yy * NQROW;
            m = rp[cq0 + lane];
            if (hq_ok) h = rp[hq];
        }
    };

    float vacc0 = 0.f, vacc1 = 0.f, vacc2 = 0.f, vacc3 = 0.f;
    float a_bce = 0.f, a_w = 0.f, a_i = 0.f, a_u = 0.f;
    int slot = 0;

    float4 e_p0, e_p1, h_p0, h_p1;
    ld_row(0, e_p0, h_p0);
    ld_row(1, e_p1, h_p1);
    float4 t_p0 = Z4, t_p1 = Z4, p_p0 = Z4, p_p1 = Z4;

    for (int step = 0; step < NSTEPS; ++step) {
        const float4 e  = e_p0;  e_p0 = e_p1;
        const float4 eh = h_p0;  h_p0 = h_p1;
        ld_row(step + 2, e_p1, h_p1);

        const float4 tcur = t_p0, pcur = p_p0;
        t_p0 = t_p1; p_p0 = p_p1;
        {
            const int s2 = step + 2;
            if (s2 >= 2 * PADK && s2 < NSTEPS) {
                const size_t off = (size_t)(r0 + (s2 - 2 * PADK)) * NQROW + cq0 + lane;
                t_p1 = targ4[off];
                p_p1 = pred4[off];
            }
        }

        const int bf = step & 1;
        ebuf[bf][QPAD + lane] = e;
        locq[bf][QPAD + lane] = e.x + e.y + e.z + e.w;
        if (lane < 8) {
            ebuf[bf][hslot] = eh;
            locq[bf][hslot] = eh.x + eh.y + eh.z + eh.w;
        }
        __builtin_amdgcn_wave_barrier();

        float F = 0.f;
        #pragma unroll
        for (int k = -3; k <= 3; ++k) F += locq[bf][lane + QPAD + k];
        const float4 L = ebuf[bf][lane];
        const float4 U = ebuf[bf][lane + 2 * QPAD];
        const float h0 = F + L.y + L.z + L.w;
        const float h1 = F + L.z + L.w + U.x;
        const float h2 = F + L.w + U.x + U.y;
        const float h3 = F + U.x + U.y + U.z;

        const __half2 n01 = __floats2half2_rn(h0, h1);
        const __half2 n23 = __floats2half2_rn(h2, h3);
        const __half2 o01 = ring[slot][0][lane];
        const __half2 o23 = ring[slot][1][lane];
        ring[slot][0][lane] = n01;
        ring[slot][1][lane] = n23;
        const float2 nf01 = __half22float2(n01), nf23 = __half22float2(n23);
        const float2 of01 = __half22float2(o01), of23 = __half22float2(o23);
        vacc0 += nf01.x - of01.x;
        vacc1 += nf01.y - of01.y;
        vacc2 += nf23.x - of23.x;
        vacc3 += nf23.y - of23.y;
        slot = (slot == 30) ? 0 : (slot + 1);

        if (step >= 2 * PADK) {
            elemwise4(vacc0, vacc1, vacc2, vacc3, tcur, pcur, a_bce, a_w, a_i, a_u);
        }
    }

    #pragma unroll
    for (int off = 32; off > 0; off >>= 1) {
        a_bce += __shfl_down(a_bce, off, 64);
        a_w   += __shfl_down(a_w,   off, 64);
        a_i   += __shfl_down(a_i,   off, 64);
        a_u   += __shfl_down(a_u,   off, 64);
    }
    if (lane == 0) {
        atomicAdd(&ws[0],      a_bce);
        atomicAdd(&ws[1 + b],  a_w);
        atomicAdd(&ws[33 + b], a_i);
        atomicAdd(&ws[65 + b], a_u);
    }
}

__global__ void finalize_kernel(const float* __restrict__ ws, float* __restrict__ out)
{
    const int i = threadIdx.x;
    float val = 0.f;
    if (i < BB) {
        const float bce   = ws[0] * (1.0f / NPIX_F);
        const float wsum  = ws[1 + i];
        const float inter = ws[33 + i];
        const float uni   = ws[65 + i];
        const float w_bce = (wsum * bce + 1e-8f) / (wsum + 1e-8f);
        const float w_iou = 1.0f - (inter + 1.0f + 1e-8f) / (uni - inter + 1.0f + 1e-8f);
        val = w_bce + w_iou;
    }
    #pragma unroll
    for (int off = 32; off > 0; off >>= 1) val += __shfl_down(val, off, 64);
    if (i == 0) out[0] = val * (1.0f / BB);
}

extern "C" void kernel_launch(void* const* d_in, const int* in_sizes, int n_in,
                              void* d_out, int out_size, void* d_ws, size_t ws_size,
                              hipStream_t stream)
{
    (void)in_sizes; (void)n_in; (void)out_size;
    const float* pred = (const float*)d_in[0];   // y_pred
    const float* targ = (const float*)d_in[1];   // y_target
    float* out = (float*)d_out;
    float* ws  = (float*)d_ws;

    if (ws_size >= WS_NEED) {
        __half* V = (__half*)((char*)d_ws + V_OFF_BYTES);
        // zero the 128 partial slots AND the completion counter at ws[128]
        hipMemsetAsync(ws, 0, 129 * sizeof(float), stream);
        hipLaunchKernelGGL(vpass_kernel, dim3(NB1), dim3(64), 0, stream,
                           targ, V);
        hipLaunchKernelGGL(hpass_kernel, dim3(NB2), dim3(128), 0, stream,
                           pred, targ, V, ws, out);
    } else {
        hipMemsetAsync(ws, 0, 97 * sizeof(float), stream);
        hipLaunchKernelGGL(fused_pool_loss_kernel,
                           dim3(BB * NSTRIPES * NCH), dim3(64), 0, stream,
                           pred, targ, ws);
        hipLaunchKernelGGL(finalize_kernel, dim3(1), dim3(64), 0, stream, ws, out);
    }
}

// Round 5
// 313.460 us; speedup vs baseline: 2.5345x; 2.5345x over previous
//
#include <hip/hip_runtime.h>
#include <hip/hip_fp16.h>

#define BB 32
#define HH 512
#define WW 512
#define NQROW (WW / 4)            // 128 float4 per row
#define NPIX_F 8388608.0f         // 32*512*512
#define QPAD 4
#define NQP (NQROW + 2 * QPAD)    // 136
#define R1 16
#define NSTR1 (HH / R1)           // 32
#define NB1 (BB * NSTR1 * 2)      // 2048 pass-1 blocks
#define ROWS2 2
#define NB2 (BB * HH / ROWS2)     // 8192 pass-2 blocks (2 waves each)
#define V_OFF_BYTES 1024
#define WS_NEED (V_OFF_BYTES + (size_t)BB * HH * WW * 2)

// two-pass ws layout (floats):
//   [0..31]   bce partials (per image)
//   [32..63]  w_sum
//   [64..95]  intersection
//   [96..127] union
// V (fp16, [B][H][W]) at byte offset 1024.

__device__ __forceinline__ void elemwise4(const float h0, const float h1,
                                          const float h2, const float h3,
                                          const float4 t, const float4 p,
                                          float& a_bce, float& a_w,
                                          float& a_i, float& a_u)
{
    const float hv[4] = {h0, h1, h2, h3};
    const float tv[4] = {t.x, t.y, t.z, t.w};
    const float pv[4] = {p.x, p.y, p.z, p.w};
    const float inv961 = (1.0f / 961.0f);
    #pragma unroll
    for (int j = 0; j < 4; ++j) {
        const float ap = hv[j] * inv961;
        const float w  = fmaf(5.0f, fabsf(ap - tv[j]), 1.0f);
        const float pr = pv[j];
        const float ea = __expf(-fabsf(pr));                  // exp(-|pr|)
        const float iv = __builtin_amdgcn_rcpf(1.0f + ea);
        const float pp = (pr >= 0.0f) ? iv : (1.0f - iv);     // sigmoid
        const float sp = fmaxf(pr, 0.0f) + __logf(1.0f + ea); // softplus
        a_bce += sp - pr * tv[j];
        a_w   += w;
        a_i   += pp * tv[j] * w;
        a_u   += (pp + tv[j]) * w;
    }
}

// ---------------- Pass 1: vertical 31-row running sums -> V (fp16) -------
__global__ __launch_bounds__(64)
void vpass_kernel(const float* __restrict__ targ, __half* __restrict__ V)
{
    const int lane = threadIdx.x;
    const int bi = blockIdx.x;
    const int halfc  = bi & 1;
    const int stripe = (bi >> 1) & (NSTR1 - 1);
    const int b      = bi >> 6;
    const int r0 = stripe * R1;
    const int cq = halfc * 64 + lane;       // quad index 0..127

    const float4* t4 = (const float4*)(targ + (size_t)b * (HH * WW));
    const float4 Z4 = make_float4(0.f, 0.f, 0.f, 0.f);
    auto ld = [&](int yy) -> float4 {
        return (yy >= 0 && yy < HH) ? t4[(size_t)yy * NQROW + cq] : Z4;
    };

    float a0 = 0.f, a1 = 0.f, a2 = 0.f, a3 = 0.f;
    float4 nb[4], sb[2];
    nb[0] = ld(r0 - 15); nb[1] = ld(r0 - 14);
    nb[2] = ld(r0 - 13); nb[3] = ld(r0 - 12);
    sb[0] = ld(r0 - 15); sb[1] = ld(r0 - 14);

    __half* Vb = V + (size_t)b * (HH * WW) + cq * 4;

    #pragma unroll
    for (int k = 0; k < 46; ++k) {          // row r0-15+k enters the window
        const float4 a = nb[k & 3];
        if (k + 4 < 46) nb[k & 3] = ld(r0 - 15 + k + 4);
        a0 += a.x; a1 += a.y; a2 += a.z; a3 += a.w;
        if (k >= 30) {
            const int y = r0 + k - 30;      // window = rows y-15..y+15
            const __half2 h01 = __floats2half2_rn(a0, a1);
            const __half2 h23 = __floats2half2_rn(a2, a3);
            uint2 pk;
            pk.x = __builtin_bit_cast(unsigned int, h01);
            pk.y = __builtin_bit_cast(unsigned int, h23);
            *(uint2*)(Vb + (size_t)y * WW) = pk;
            const float4 s = sb[k & 1];
            if (k + 2 < 46) sb[k & 1] = ld(r0 + k - 43);
            a0 -= s.x; a1 -= s.y; a2 -= s.z; a3 -= s.w;
        }
    }
}

// -------- Pass 2: horizontal 31-sum + elementwise + per-image reduce -----
__global__ __launch_bounds__(128)
void hpass_kernel(const float* __restrict__ pred, const float* __restrict__ targ,
                  const __half* __restrict__ V, float* __restrict__ ws)
{
    const int lane = threadIdx.x & 63;
    const int wv   = threadIdx.x >> 6;              // 0..1, independent waves
    const int gr   = blockIdx.x * ROWS2 + wv;       // global row id
    const int b = gr >> 9;

    __shared__ float4 ebuf[ROWS2][NQP];
    __shared__ float  locq[ROWS2][NQP];

    const float4 Z4 = make_float4(0.f, 0.f, 0.f, 0.f);
    if (lane < 2 * QPAD) {                          // zero x-halo pads
        const int idx = (lane < QPAD) ? lane : (NQROW + lane);
        ebuf[wv][idx] = Z4;
        locq[wv][idx] = 0.f;
    }

    // issue ALL global loads up front (one latency exposure per wave)
    const size_t rowoff = (size_t)gr * WW;
    const uint4 vv = ((const uint4*)(V + rowoff))[lane];   // 8 fp16
    const float4* t4 = (const float4*)(targ + rowoff);
    const float4* p4 = (const float4*)(pred + rowoff);
    const float4 tA = t4[lane], tB = t4[64 + lane];
    const float4 pA = p4[lane], pB = p4[64 + lane];

    // unpack V -> cols 8*lane .. 8*lane+7 = quads 2*lane, 2*lane+1
    const __half2 v01 = __builtin_bit_cast(__half2, vv.x);
    const __half2 v23 = __builtin_bit_cast(__half2, vv.y);
    const __half2 v45 = __builtin_bit_cast(__half2, vv.z);
    const __half2 v67 = __builtin_bit_cast(__half2, vv.w);
    const float2 f01 = __half22float2(v01), f23 = __half22float2(v23);
    const float2 f45 = __half22float2(v45), f67 = __half22float2(v67);
    const float4 lo = make_float4(f01.x, f01.y, f23.x, f23.y);
    const float4 hi = make_float4(f45.x, f45.y, f67.x, f67.y);
    ebuf[wv][QPAD + 2 * lane]     = lo;
    locq[wv][QPAD + 2 * lane]     = lo.x + lo.y + lo.z + lo.w;
    ebuf[wv][QPAD + 2 * lane + 1] = hi;
    locq[wv][QPAD + 2 * lane + 1] = hi.x + hi.y + hi.z + hi.w;
    __builtin_amdgcn_wave_barrier();   // single-wave LDS exchange; lgkmcnt
                                       // ordering inserted by the compiler

    float a_bce = 0.f, a_w = 0.f, a_i = 0.f, a_u = 0.f;
    #pragma unroll
    for (int half2_ = 0; half2_ < 2; ++half2_) {
        const int q = half2_ * 64 + lane;           // owned quad
        float F = 0.f;
        #pragma unroll
        for (int k = -3; k <= 3; ++k) F += locq[wv][QPAD + q + k];
        const float4 L = ebuf[wv][QPAD + q - 4];
        const float4 U = ebuf[wv][QPAD + q + 4];
        const float h0 = F + L.y + L.z + L.w;       // col 4q: [4q-15..4q+15]
        const float h1 = F + L.z + L.w + U.x;
        const float h2 = F + L.w + U.x + U.y;
        const float h3 = F + U.x + U.y + U.z;
        elemwise4(h0, h1, h2, h3,
                  half2_ ? tB : tA, half2_ ? pB : pA,
                  a_bce, a_w, a_i, a_u);
    }

    #pragma unroll
    for (int off = 32; off > 0; off >>= 1) {
        a_bce += __shfl_down(a_bce, off, 64);
        a_w   += __shfl_down(a_w,   off, 64);
        a_i   += __shfl_down(a_i,   off, 64);
        a_u   += __shfl_down(a_u,   off, 64);
    }
    if (lane == 0) {
        atomicAdd(&ws[b],      a_bce);   // device-scope by default; kernel
        atomicAdd(&ws[32 + b], a_w);     // boundary orders vs finalize
        atomicAdd(&ws[64 + b], a_i);
        atomicAdd(&ws[96 + b], a_u);
    }
}

__global__ void finalize2_kernel(const float* __restrict__ ws, float* __restrict__ out)
{
    const int i = threadIdx.x;
    float bsum = (i < 32) ? ws[i] : 0.f;
    #pragma unroll
    for (int off = 32; off > 0; off >>= 1) bsum += __shfl_down(bsum, off, 64);
    const float bce = __shfl(bsum, 0, 64) * (1.0f / NPIX_F);

    float val = 0.f;
    if (i < BB) {
        const float wsum  = ws[32 + i];
        const float inter = ws[64 + i];
        const float uni   = ws[96 + i];
        const float w_bce = (wsum * bce + 1e-8f) / (wsum + 1e-8f);
        const float w_iou = 1.0f - (inter + 1.0f + 1e-8f) / (uni - inter + 1.0f + 1e-8f);
        val = w_bce + w_iou;
    }
    #pragma unroll
    for (int off = 32; off > 0; off >>= 1) val += __shfl_down(val, off, 64);
    if (i == 0) out[0] = val * (1.0f / BB);
}

// ================= fallback (validated round-2 fused path) ===============
#define PADK 15
#define RROWS 32
#define NSTRIPES (HH / RROWS)
#define NCH 2
#define COLS (WW / NCH)
#define CQ (COLS / 4)
#define FNQP (CQ + 2 * QPAD)
#define NSTEPS (RROWS + 2 * PADK)

__global__ __launch_bounds__(64)
void fused_pool_loss_kernel(const float* __restrict__ pred,
                            const float* __restrict__ targ,
                            float* __restrict__ ws)
{
    const int lane = threadIdx.x;
    const int bi   = blockIdx.x;
    const int half   = bi & 1;
    const int stripe = (bi >> 1) & (NSTRIPES - 1);
    const int b      = bi >> 5;
    const int r0  = stripe * RROWS;
    const int cq0 = half * CQ;

    __shared__ __half2 ring[31][2][64];
    __shared__ float4  ebuf[2][FNQP];
    __shared__ float   locq[2][FNQP];

    {
        const __half2 z2 = __floats2half2_rn(0.f, 0.f);
        __half2* rp = &ring[0][0][0];
        for (int i = lane; i < 31 * 2 * 64; i += 64) rp[i] = z2;
    }
    __builtin_amdgcn_wave_barrier();

    const float4* targ4 = (const float4*)(targ + (size_t)b * HH * WW);
    const float4* pred4 = (const float4*)(pred + (size_t)b * HH * WW);
    const float4 Z4 = make_float4(0.f, 0.f, 0.f, 0.f);

    const int hq = (lane < 4) ? (cq0 - QPAD + lane) : (cq0 + CQ + (lane - 4));
    const bool hq_ok = (lane < 8) && (hq >= 0) && (hq < NQROW);
    const int hslot = (lane < 4) ? lane : (CQ + QPAD + (lane - 4));

    auto ld_row = [&](int step, float4& m, float4& h) {
        m = Z4; h = Z4;
        const int yy = r0 - PADK + step;
        if (step < NSTEPS && yy >= 0 && yy < HH) {
            const float4* rp = targ4 + (size_t)yy * NQROW;
            m = rp[cq0 + lane];
            if (hq_ok) h = rp[hq];
        }
    };

    float vacc0 = 0.f, vacc1 = 0.f, vacc2 = 0.f, vacc3 = 0.f;
    float a_bce = 0.f, a_w = 0.f, a_i = 0.f, a_u = 0.f;
    int slot = 0;

    float4 e_p0, e_p1, h_p0, h_p1;
    ld_row(0, e_p0, h_p0);
    ld_row(1, e_p1, h_p1);
    float4 t_p0 = Z4, t_p1 = Z4, p_p0 = Z4, p_p1 = Z4;

    for (int step = 0; step < NSTEPS; ++step) {
        const float4 e  = e_p0;  e_p0 = e_p1;
        const float4 eh = h_p0;  h_p0 = h_p1;
        ld_row(step + 2, e_p1, h_p1);

        const float4 tcur = t_p0, pcur = p_p0;
        t_p0 = t_p1; p_p0 = p_p1;
        {
            const int s2 = step + 2;
            if (s2 >= 2 * PADK && s2 < NSTEPS) {
                const size_t off = (size_t)(r0 + (s2 - 2 * PADK)) * NQROW + cq0 + lane;
                t_p1 = targ4[off];
                p_p1 = pred4[off];
            }
        }

        const int bf = step & 1;
        ebuf[bf][QPAD + lane] = e;
        locq[bf][QPAD + lane] = e.x + e.y + e.z + e.w;
        if (lane < 8) {
            ebuf[bf][hslot] = eh;
            locq[bf][hslot] = eh.x + eh.y + eh.z + eh.w;
        }
        __builtin_amdgcn_wave_barrier();

        float F = 0.f;
        #pragma unroll
        for (int k = -3; k <= 3; ++k) F += locq[bf][lane + QPAD + k];
        const float4 L = ebuf[bf][lane];
        const float4 U = ebuf[bf][lane + 2 * QPAD];
        const float h0 = F + L.y + L.z + L.w;
        const float h1 = F + L.z + L.w + U.x;
        const float h2 = F + L.w + U.x + U.y;
        const float h3 = F + U.x + U.y + U.z;

        const __half2 n01 = __floats2half2_rn(h0, h1);
        const __half2 n23 = __floats2half2_rn(h2, h3);
        const __half2 o01 = ring[slot][0][lane];
        const __half2 o23 = ring[slot][1][lane];
        ring[slot][0][lane] = n01;
        ring[slot][1][lane] = n23;
        const float2 nf01 = __half22float2(n01), nf23 = __half22float2(n23);
        const float2 of01 = __half22float2(o01), of23 = __half22float2(o23);
        vacc0 += nf01.x - of01.x;
        vacc1 += nf01.y - of01.y;
        vacc2 += nf23.x - of23.x;
        vacc3 += nf23.y - of23.y;
        slot = (slot == 30) ? 0 : (slot + 1);

        if (step >= 2 * PADK) {
            elemwise4(vacc0, vacc1, vacc2, vacc3, tcur, pcur, a_bce, a_w, a_i, a_u);
        }
    }

    #pragma unroll
    for (int off = 32; off > 0; off >>= 1) {
        a_bce += __shfl_down(a_bce, off, 64);
        a_w   += __shfl_down(a_w,   off, 64);
        a_i   += __shfl_down(a_i,   off, 64);
        a_u   += __shfl_down(a_u,   off, 64);
    }
    if (lane == 0) {
        atomicAdd(&ws[0],      a_bce);
        atomicAdd(&ws[1 + b],  a_w);
        atomicAdd(&ws[33 + b], a_i);
        atomicAdd(&ws[65 + b], a_u);
    }
}

__global__ void finalize_kernel(const float* __restrict__ ws, float* __restrict__ out)
{
    const int i = threadIdx.x;
    float val = 0.f;
    if (i < BB) {
        const float bce   = ws[0] * (1.0f / NPIX_F);
        const float wsum  = ws[1 + i];
        const float inter = ws[33 + i];
        const float uni   = ws[65 + i];
        const float w_bce = (wsum * bce + 1e-8f) / (wsum + 1e-8f);
        const float w_iou = 1.0f - (inter + 1.0f + 1e-8f) / (uni - inter + 1.0f + 1e-8f);
        val = w_bce + w_iou;
    }
    #pragma unroll
    for (int off = 32; off > 0; off >>= 1) val += __shfl_down(val, off, 64);
    if (i == 0) out[0] = val * (1.0f / BB);
}

extern "C" void kernel_launch(void* const* d_in, const int* in_sizes, int n_in,
                              void* d_out, int out_size, void* d_ws, size_t ws_size,
                              hipStream_t stream)
{
    (void)in_sizes; (void)n_in; (void)out_size;
    const float* pred = (const float*)d_in[0];   // y_pred
    const float* targ = (const float*)d_in[1];   // y_target
    float* out = (float*)d_out;
    float* ws  = (float*)d_ws;

    if (ws_size >= WS_NEED) {
        __half* V = (__half*)((char*)d_ws + V_OFF_BYTES);
        hipMemsetAsync(ws, 0, 128 * sizeof(float), stream);
        hipLaunchKernelGGL(vpass_kernel, dim3(NB1), dim3(64), 0, stream,
                           targ, V);
        hipLaunchKernelGGL(hpass_kernel, dim3(NB2), dim3(128), 0, stream,
                           pred, targ, V, ws);
        hipLaunchKernelGGL(finalize2_kernel, dim3(1), dim3(64), 0, stream, ws, out);
    } else {
        hipMemsetAsync(ws, 0, 97 * sizeof(float), stream);
        hipLaunchKernelGGL(fused_pool_loss_kernel,
                           dim3(BB * NSTRIPES * NCH), dim3(64), 0, stream,
                           pred, targ, ws);
        hipLaunchKernelGGL(finalize_kernel, dim3(1), dim3(64), 0, stream, ws, out);
    }
}

// Round 6
// 128.647 us; speedup vs baseline: 6.1755x; 2.4366x over previous
//
#include <hip/hip_runtime.h>
#include <hip/hip_fp16.h>

#define BB 32
#define HH 512
#define WW 512
#define NQROW (WW / 4)            // 128 float4 per row
#define NPIX_F 8388608.0f         // 32*512*512
#define QPAD 4
#define NQP (NQROW + 2 * QPAD)    // 136
#define R1 8
#define NSTR1 (HH / R1)           // 64
#define NB1 (BB * NSTR1 * 2)      // 4096 pass-1 blocks (1 wave each)
#define NROWS1 (R1 + 30)          // 38 input rows per stripe
#define ROWS2 2
#define NB2 (BB * HH / ROWS2)     // 8192 pass-2 blocks (2 waves each)
#define PART_BYTES (NB2 * 16)     // 8192 float4 partials = 128 KiB
#define V_OFF_BYTES PART_BYTES
#define WS_NEED (V_OFF_BYTES + (size_t)BB * HH * WW * 2)

// two-pass ws layout:
//   [0 .. 128K)  float4 per-block partials {bce, w, inter, union} (non-atomic)
//   [128K .. )   V (fp16, [B][H][W]) vertical 31-row sums

__device__ __forceinline__ void elemwise4(const float h0, const float h1,
                                          const float h2, const float h3,
                                          const float4 t, const float4 p,
                                          float& a_bce, float& a_w,
                                          float& a_i, float& a_u)
{
    const float hv[4] = {h0, h1, h2, h3};
    const float tv[4] = {t.x, t.y, t.z, t.w};
    const float pv[4] = {p.x, p.y, p.z, p.w};
    const float inv961 = (1.0f / 961.0f);
    #pragma unroll
    for (int j = 0; j < 4; ++j) {
        const float ap = hv[j] * inv961;
        const float w  = fmaf(5.0f, fabsf(ap - tv[j]), 1.0f);
        const float pr = pv[j];
        const float ea = __expf(-fabsf(pr));                  // exp(-|pr|)
        const float iv = __builtin_amdgcn_rcpf(1.0f + ea);
        const float pp = (pr >= 0.0f) ? iv : (1.0f - iv);     // sigmoid
        const float sp = fmaxf(pr, 0.0f) + __logf(1.0f + ea); // softplus
        a_bce += sp - pr * tv[j];
        a_w   += w;
        a_i   += pp * tv[j] * w;
        a_u   += (pp + tv[j]) * w;
    }
}

// ---------------- Pass 1: vertical 31-row running sums -> V (fp16) -------
// One wave per (image, 8-row stripe, column half). Depth-8 prefetch ring;
// the first 8 rows (the ones that exit the window) are kept in registers.
__global__ __launch_bounds__(64)
void vpass_kernel(const float* __restrict__ targ, __half* __restrict__ V)
{
    const int lane = threadIdx.x;
    const int bi = blockIdx.x;
    const int halfc  = bi & 1;
    const int stripe = (bi >> 1) & (NSTR1 - 1);
    const int b      = bi >> 7;             // 1+6+5 bits = 4096 blocks
    const int r0 = stripe * R1;
    const int cq = halfc * 64 + lane;       // quad index 0..127

    const float4* t4 = (const float4*)(targ + (size_t)b * (HH * WW));
    const float4 Z4 = make_float4(0.f, 0.f, 0.f, 0.f);
    auto ld = [&](int yy) -> float4 {
        return (yy >= 0 && yy < HH) ? t4[(size_t)yy * NQROW + cq] : Z4;
    };

    float4 buf[8];                           // prefetch ring (8 outstanding)
    float4 sv[8];                            // saved rows r0-15 .. r0-8
    #pragma unroll
    for (int i = 0; i < 8; ++i) buf[i] = ld(r0 - 15 + i);

    float a0 = 0.f, a1 = 0.f, a2 = 0.f, a3 = 0.f;
    __half* Vb = V + (size_t)b * (HH * WW) + cq * 4;

    #pragma unroll
    for (int k = 0; k < NROWS1; ++k) {      // row r0-15+k enters the window
        const float4 a = buf[k & 7];
        if (k < 8) sv[k] = a;
        if (k + 8 < NROWS1) buf[k & 7] = ld(r0 - 15 + k + 8);
        a0 += a.x; a1 += a.y; a2 += a.z; a3 += a.w;
        if (k >= 30) {
            const int y = r0 + k - 30;      // window = rows y-15..y+15
            const __half2 h01 = __floats2half2_rn(a0, a1);
            const __half2 h23 = __floats2half2_rn(a2, a3);
            uint2 pk;
            pk.x = __builtin_bit_cast(unsigned int, h01);
            pk.y = __builtin_bit_cast(unsigned int, h23);
            *(uint2*)(Vb + (size_t)y * WW) = pk;
            const float4 s = sv[k - 30];    // row y-15 leaves the window
            a0 -= s.x; a1 -= s.y; a2 -= s.z; a3 -= s.w;
        }
    }
}

// -------- Pass 2: horizontal 31-sum + elementwise + per-block partial ----
__global__ __launch_bounds__(128)
void hpass_kernel(const float* __restrict__ pred, const float* __restrict__ targ,
                  const __half* __restrict__ V, float4* __restrict__ part)
{
    const int lane = threadIdx.x & 63;
    const int wv   = threadIdx.x >> 6;              // 0..1, independent waves
    const int gr   = blockIdx.x * ROWS2 + wv;       // global row id

    __shared__ float4 ebuf[ROWS2][NQP];
    __shared__ float  locq[ROWS2][NQP];
    __shared__ float4 comb[ROWS2];

    const float4 Z4 = make_float4(0.f, 0.f, 0.f, 0.f);
    if (lane < 2 * QPAD) {                          // zero x-halo pads
        const int idx = (lane < QPAD) ? lane : (NQROW + lane);
        ebuf[wv][idx] = Z4;
        locq[wv][idx] = 0.f;
    }

    // issue ALL global loads up front (one latency exposure per wave)
    const size_t rowoff = (size_t)gr * WW;
    const uint4 vv = ((const uint4*)(V + rowoff))[lane];   // 8 fp16
    const float4* t4 = (const float4*)(targ + rowoff);
    const float4* p4 = (const float4*)(pred + rowoff);
    const float4 tA = t4[lane], tB = t4[64 + lane];
    const float4 pA = p4[lane], pB = p4[64 + lane];

    // unpack V -> cols 8*lane .. 8*lane+7 = quads 2*lane, 2*lane+1
    const __half2 v01 = __builtin_bit_cast(__half2, vv.x);
    const __half2 v23 = __builtin_bit_cast(__half2, vv.y);
    const __half2 v45 = __builtin_bit_cast(__half2, vv.z);
    const __half2 v67 = __builtin_bit_cast(__half2, vv.w);
    const float2 f01 = __half22float2(v01), f23 = __half22float2(v23);
    const float2 f45 = __half22float2(v45), f67 = __half22float2(v67);
    const float4 lo = make_float4(f01.x, f01.y, f23.x, f23.y);
    const float4 hi = make_float4(f45.x, f45.y, f67.x, f67.y);
    ebuf[wv][QPAD + 2 * lane]     = lo;
    locq[wv][QPAD + 2 * lane]     = lo.x + lo.y + lo.z + lo.w;
    ebuf[wv][QPAD + 2 * lane + 1] = hi;
    locq[wv][QPAD + 2 * lane + 1] = hi.x + hi.y + hi.z + hi.w;
    __builtin_amdgcn_wave_barrier();   // single-wave LDS exchange; lgkmcnt
                                       // ordering inserted by the compiler

    float a_bce = 0.f, a_w = 0.f, a_i = 0.f, a_u = 0.f;
    #pragma unroll
    for (int hf = 0; hf < 2; ++hf) {
        const int q = hf * 64 + lane;               // owned quad
        float F = 0.f;
        #pragma unroll
        for (int k = -3; k <= 3; ++k) F += locq[wv][QPAD + q + k];
        const float4 L = ebuf[wv][QPAD + q - 4];
        const float4 U = ebuf[wv][QPAD + q + 4];
        const float h0 = F + L.y + L.z + L.w;       // col 4q: [4q-15..4q+15]
        const float h1 = F + L.z + L.w + U.x;
        const float h2 = F + L.w + U.x + U.y;
        const float h3 = F + U.x + U.y + U.z;
        elemwise4(h0, h1, h2, h3,
                  hf ? tB : tA, hf ? pB : pA,
                  a_bce, a_w, a_i, a_u);
    }

    #pragma unroll
    for (int off = 32; off > 0; off >>= 1) {
        a_bce += __shfl_down(a_bce, off, 64);
        a_w   += __shfl_down(a_w,   off, 64);
        a_i   += __shfl_down(a_i,   off, 64);
        a_u   += __shfl_down(a_u,   off, 64);
    }
    if (lane == 0) comb[wv] = make_float4(a_bce, a_w, a_i, a_u);
    __syncthreads();                     // once per block, at kernel end
    if (threadIdx.x == 0) {
        const float4 c0 = comb[0], c1 = comb[1];
        part[blockIdx.x] = make_float4(c0.x + c1.x, c0.y + c1.y,
                                       c0.z + c1.z, c0.w + c1.w);
    }
}

// ---- Finalize: deterministic tree over 8192 partials, then the scalar ---
__global__ __launch_bounds__(1024)
void finalize2_kernel(const float4* __restrict__ part, float* __restrict__ out)
{
    const int lane = threadIdx.x & 63;
    const int w    = threadIdx.x >> 6;      // 16 waves; each handles 2 images
    __shared__ float4 sums[BB];

    #pragma unroll
    for (int s = 0; s < 2; ++s) {
        const int img = w * 2 + s;
        const int base = img * 256;         // 256 partials per image
        float4 acc = make_float4(0.f, 0.f, 0.f, 0.f);
        #pragma unroll
        for (int j = 0; j < 4; ++j) {
            const float4 v = part[base + j * 64 + lane];
            acc.x += v.x; acc.y += v.y; acc.z += v.z; acc.w += v.w;
        }
        #pragma unroll
        for (int off = 32; off > 0; off >>= 1) {
            acc.x += __shfl_down(acc.x, off, 64);
            acc.y += __shfl_down(acc.y, off, 64);
            acc.z += __shfl_down(acc.z, off, 64);
            acc.w += __shfl_down(acc.w, off, 64);
        }
        if (lane == 0) sums[img] = acc;
    }
    __syncthreads();

    if (w == 0) {
        float bsum = (lane < BB) ? sums[lane].x : 0.f;
        #pragma unroll
        for (int off = 32; off > 0; off >>= 1) bsum += __shfl_down(bsum, off, 64);
        const float bce = __shfl(bsum, 0, 64) * (1.0f / NPIX_F);

        float val = 0.f;
        if (lane < BB) {
            const float wsum  = sums[lane].y;
            const float inter = sums[lane].z;
            const float uni   = sums[lane].w;
            const float w_bce = (wsum * bce + 1e-8f) / (wsum + 1e-8f);
            const float w_iou = 1.0f - (inter + 1.0f + 1e-8f) / (uni - inter + 1.0f + 1e-8f);
            val = w_bce + w_iou;
        }
        #pragma unroll
        for (int off = 32; off > 0; off >>= 1) val += __shfl_down(val, off, 64);
        if (lane == 0) out[0] = val * (1.0f / BB);
    }
}

// ================= fallback (validated round-2 fused path) ===============
#define PADK 15
#define RROWS 32
#define NSTRIPES (HH / RROWS)
#define NCH 2
#define COLS (WW / NCH)
#define CQ (COLS / 4)
#define FNQP (CQ + 2 * QPAD)
#define NSTEPS (RROWS + 2 * PADK)

__global__ __launch_bounds__(64)
void fused_pool_loss_kernel(const float* __restrict__ pred,
                            const float* __restrict__ targ,
                            float* __restrict__ ws)
{
    const int lane = threadIdx.x;
    const int bi   = blockIdx.x;
    const int half   = bi & 1;
    const int stripe = (bi >> 1) & (NSTRIPES - 1);
    const int b      = bi >> 5;
    const int r0  = stripe * RROWS;
    const int cq0 = half * CQ;

    __shared__ __half2 ring[31][2][64];
    __shared__ float4  ebuf[2][FNQP];
    __shared__ float   locq[2][FNQP];

    {
        const __half2 z2 = __floats2half2_rn(0.f, 0.f);
        __half2* rp = &ring[0][0][0];
        for (int i = lane; i < 31 * 2 * 64; i += 64) rp[i] = z2;
    }
    __builtin_amdgcn_wave_barrier();

    const float4* targ4 = (const float4*)(targ + (size_t)b * HH * WW);
    const float4* pred4 = (const float4*)(pred + (size_t)b * HH * WW);
    const float4 Z4 = make_float4(0.f, 0.f, 0.f, 0.f);

    const int hq = (lane < 4) ? (cq0 - QPAD + lane) : (cq0 + CQ + (lane - 4));
    const bool hq_ok = (lane < 8) && (hq >= 0) && (hq < NQROW);
    const int hslot = (lane < 4) ? lane : (CQ + QPAD + (lane - 4));

    auto ld_row = [&](int step, float4& m, float4& h) {
        m = Z4; h = Z4;
        const int yy = r0 - PADK + step;
        if (step < NSTEPS && yy >= 0 && yy < HH) {
            const float4* rp = targ4 + (size_t)yy * NQROW;
            m = rp[cq0 + lane];
            if (hq_ok) h = rp[hq];
        }
    };

    float vacc0 = 0.f, vacc1 = 0.f, vacc2 = 0.f, vacc3 = 0.f;
    float a_bce = 0.f, a_w = 0.f, a_i = 0.f, a_u = 0.f;
    int slot = 0;

    float4 e_p0, e_p1, h_p0, h_p1;
    ld_row(0, e_p0, h_p0);
    ld_row(1, e_p1, h_p1);
    float4 t_p0 = Z4, t_p1 = Z4, p_p0 = Z4, p_p1 = Z4;

    for (int step = 0; step < NSTEPS; ++step) {
        const float4 e  = e_p0;  e_p0 = e_p1;
        const float4 eh = h_p0;  h_p0 = h_p1;
        ld_row(step + 2, e_p1, h_p1);

        const float4 tcur = t_p0, pcur = p_p0;
        t_p0 = t_p1; p_p0 = p_p1;
        {
            const int s2 = step + 2;
            if (s2 >= 2 * PADK && s2 < NSTEPS) {
                const size_t off = (size_t)(r0 + (s2 - 2 * PADK)) * NQROW + cq0 + lane;
                t_p1 = targ4[off];
                p_p1 = pred4[off];
            }
        }

        const int bf = step & 1;
        ebuf[bf][QPAD + lane] = e;
        locq[bf][QPAD + lane] = e.x + e.y + e.z + e.w;
        if (lane < 8) {
            ebuf[bf][hslot] = eh;
            locq[bf][hslot] = eh.x + eh.y + eh.z + eh.w;
        }
        __builtin_amdgcn_wave_barrier();

        float F = 0.f;
        #pragma unroll
        for (int k = -3; k <= 3; ++k) F += locq[bf][lane + QPAD + k];
        const float4 L = ebuf[bf][lane];
        const float4 U = ebuf[bf][lane + 2 * QPAD];
        const float h0 = F + L.y + L.z + L.w;
        const float h1 = F + L.z + L.w + U.x;
        const float h2 = F + L.w + U.x + U.y;
        const float h3 = F + U.x + U.y + U.z;

        const __half2 n01 = __floats2half2_rn(h0, h1);
        const __half2 n23 = __floats2half2_rn(h2, h3);
        const __half2 o01 = ring[slot][0][lane];
        const __half2 o23 = ring[slot][1][lane];
        ring[slot][0][lane] = n01;
        ring[slot][1][lane] = n23;
        const float2 nf01 = __half22float2(n01), nf23 = __half22float2(n23);
        const float2 of01 = __half22float2(o01), of23 = __half22float2(o23);
        vacc0 += nf01.x - of01.x;
        vacc1 += nf01.y - of01.y;
        vacc2 += nf23.x - of23.x;
        vacc3 += nf23.y - of23.y;
        slot = (slot == 30) ? 0 : (slot + 1);

        if (step >= 2 * PADK) {
            elemwise4(vacc0, vacc1, vacc2, vacc3, tcur, pcur, a_bce, a_w, a_i, a_u);
        }
    }

    #pragma unroll
    for (int off = 32; off > 0; off >>= 1) {
        a_bce += __shfl_down(a_bce, off, 64);
        a_w   += __shfl_down(a_w,   off, 64);
        a_i   += __shfl_down(a_i,   off, 64);
        a_u   += __shfl_down(a_u,   off, 64);
    }
    if (lane == 0) {
        atomicAdd(&ws[0],      a_bce);
        atomicAdd(&ws[1 + b],  a_w);
        atomicAdd(&ws[33 + b], a_i);
        atomicAdd(&ws[65 + b], a_u);
    }
}

__global__ void finalize_kernel(const float* __restrict__ ws, float* __restrict__ out)
{
    const int i = threadIdx.x;
    float val = 0.f;
    if (i < BB) {
        const float bce   = ws[0] * (1.0f / NPIX_F);
        const float wsum  = ws[1 + i];
        const float inter = ws[33 + i];
        const float uni   = ws[65 + i];
        const float w_bce = (wsum * bce + 1e-8f) / (wsum + 1e-8f);
        const float w_iou = 1.0f - (inter + 1.0f + 1e-8f) / (uni - inter + 1.0f + 1e-8f);
        val = w_bce + w_iou;
    }
    #pragma unroll
    for (int off = 32; off > 0; off >>= 1) val += __shfl_down(val, off, 64);
    if (i == 0) out[0] = val * (1.0f / BB);
}

extern "C" void kernel_launch(void* const* d_in, const int* in_sizes, int n_in,
                              void* d_out, int out_size, void* d_ws, size_t ws_size,
                              hipStream_t stream)
{
    (void)in_sizes; (void)n_in; (void)out_size;
    const float* pred = (const float*)d_in[0];   // y_pred
    const float* targ = (const float*)d_in[1];   // y_target
    float* out = (float*)d_out;
    float* ws  = (float*)d_ws;

    if (ws_size >= WS_NEED) {
        float4* part = (float4*)d_ws;
        __half* V = (__half*)((char*)d_ws + V_OFF_BYTES);
        hipLaunchKernelGGL(vpass_kernel, dim3(NB1), dim3(64), 0, stream,
                           targ, V);
        hipLaunchKernelGGL(hpass_kernel, dim3(NB2), dim3(128), 0, stream,
                           pred, targ, V, part);
        hipLaunchKernelGGL(finalize2_kernel, dim3(1), dim3(1024), 0, stream,
                           part, out);
    } else {
        hipMemsetAsync(ws, 0, 97 * sizeof(float), stream);
        hipLaunchKernelGGL(fused_pool_loss_kernel,
                           dim3(BB * NSTRIPES * NCH), dim3(64), 0, stream,
                           pred, targ, ws);
        hipLaunchKernelGGL(finalize_kernel, dim3(1), dim3(64), 0, stream, ws, out);
    }
}